// Round 4
// baseline (248.588 us; speedup 1.0000x reference)
//
#include <hip/hip_runtime.h>
#include <stdint.h>

#define Mdim 4096
#define Kdim 4096
#define Ndim 4096

typedef __attribute__((ext_vector_type(4))) int v4i;
typedef __attribute__((ext_vector_type(16))) int v16i;

__device__ __forceinline__ void gload_lds16(const void* g, void* l) {
  __builtin_amdgcn_global_load_lds(
      (__attribute__((address_space(1))) void*)(uintptr_t)g,
      (__attribute__((address_space(3))) void*)(uint32_t)(uintptr_t)l,
      16, 0, 0);
}

// ---- pack x (int32 [M][K] -> int8 [M][K]) + row sums -----------------------
__global__ __launch_bounds__(256) void pack_x_kernel(const int* __restrict__ x,
                                                     char* __restrict__ x8,
                                                     int* __restrict__ rsx) {
  const int row = blockIdx.x;
  const int t = threadIdx.x;
  const int4* src = (const int4*)(x + (size_t)row * Kdim);
  int* dst = (int*)(x8 + (size_t)row * Kdim);
  int sum = 0;
#pragma unroll
  for (int i = 0; i < 4; ++i) {
    int4 v = src[t + 256 * i];
    sum += v.x + v.y + v.z + v.w;
    dst[t + 256 * i] =
        (v.x & 0xff) | ((v.y & 0xff) << 8) | ((v.z & 0xff) << 16) | (v.w << 24);
  }
#pragma unroll
  for (int o = 32; o > 0; o >>= 1) sum += __shfl_down(sum, o, 64);
  __shared__ int red[4];
  if ((t & 63) == 0) red[t >> 6] = sum;
  __syncthreads();
  if (t == 0) rsx[row] = red[0] + red[1] + red[2] + red[3];
}

// ---- pack + transpose y: int32 [K][N] -> int8 (y-128) in MFMA B-FRAGMENT
// order + colsum. Fragment layout (matches gemm's direct register loads):
//   addr(nblk, kt, ks, lane) = nblk*131072 + kt*2048 + ks*1024 + lane*16
//   lane = ((k>>4)&1)*32 + (n&31), holding B^T[n][k..k+15] (k-packed bytes).
// Same data bytes as before; only the store address map changed.
__global__ __launch_bounds__(256) void pack_yt_kernel(const int* __restrict__ y,
                                                      char* __restrict__ yt,
                                                      int* __restrict__ csy) {
  __shared__ int wt[64 * 17];
  const int t = threadIdx.x;
  const int n0 = blockIdx.x * 64;
  const int k0 = blockIdx.y * 64;
  const int c = t & 15;   // n-quad
  const int r0 = t >> 4;  // 0..15
#pragma unroll
  for (int s = 0; s < 4; ++s) {
    const int r = r0 + s * 16;  // k row 0..63
    int4 v = *(const int4*)(y + (size_t)(k0 + r) * Ndim + n0 + c * 4);
    v.x -= 128; v.y -= 128; v.z -= 128; v.w -= 128;
    wt[r * 17 + c] =
        (v.x & 0xff) | ((v.y & 0xff) << 8) | ((v.z & 0xff) << 16) | (v.w << 24);
  }
  __syncthreads();
  const int n = t >> 2;        // 0..63
  const int kq = t & 3;        // 16-k chunk
  const int colw = n >> 2;     // LDS word column
  const int byi = (n & 3) * 8; // byte select
  int outw[4];
  int bsum = 0;
#pragma unroll
  for (int j = 0; j < 4; ++j) {
    int b[4];
#pragma unroll
    for (int jj = 0; jj < 4; ++jj) {
      const int word = wt[(kq * 16 + j * 4 + jj) * 17 + colw];
      b[jj] = (word >> byi) & 0xff;
      bsum += (int)(char)b[jj];
    }
    outw[j] = b[0] | (b[1] << 8) | (b[2] << 16) | (b[3] << 24);
  }
  // Fragment-order store (was row-major yt[n][k]).
  {
    const int n_abs = n0 + n;
    const int k_abs = k0 + kq * 16;
    const int nblk = n_abs >> 5;
    const int lane16 = ((k_abs >> 4) & 1) * 32 + (n_abs & 31);
    const int kt_ = k_abs >> 6;
    const int ks_ = (k_abs >> 5) & 1;
    *(int4*)(yt + (size_t)nblk * 131072 + kt_ * 2048 + ks_ * 1024 +
             lane16 * 16) = make_int4(outw[0], outw[1], outw[2], outw[3]);
  }
  bsum += __shfl_xor(bsum, 1, 64);
  bsum += __shfl_xor(bsum, 2, 64);
  if (kq == 0) atomicAdd(csy + n0 + n, bsum);
}

// ---- i8 GEMM: C = 7.5e-4*(A8 @ B8^T - 32*rsx[m] + 66*csy[n] - 2112*K) ------
// 512 thr / 8 waves, tile 256x256, BK=64, 2 waves/SIMD.
// LDS-pressure fix: B operand loads DIRECTLY from global (fragment-packed by
// pack_yt) into registers -> LDS pipe/tile drops 1790->~640 cy, below the
// 1171-cy MFMA floor. A stays in LDS (reused x2 waves), 4 x 16KB buffers.
// Per tile: READF_A(next bank, 4 ds_read) | READ_B(next bank, 8 dwordx4 from
// L2-resident frags) | STG_A(tile+3, 2 gload_lds) | WAITV(10) (certifies this
// tile's B + A-staging(+2); robust to load reordering: exactly 10 vmem ops
// between fences) | 16 MFMA | BAR.
// XCD remap: linear block d -> xcd=d&7 owns bn pair {2x,2x+1} -> B working
// set 2MB per XCD L2 (4MB). Bijective for the 256-block grid.
__global__ __launch_bounds__(512, 2) void gemm_i8_kernel(
    const char* __restrict__ A, const char* __restrict__ B,
    const int* __restrict__ rsx, const int* __restrict__ csy,
    float* __restrict__ out) {
  __shared__ __align__(16) char lds[4 * 16384];  // A tiles only
  const int t = threadIdx.x;
  const int l = t & 63;
  const int w = t >> 6;      // 0..7
  const int warow = w >> 1;  // 0..3 (x64 rows)
  const int wbcol = w & 1;   // 0..1 (x128 cols)
  // XCD-aware remap (perf heuristic only; bijective on 16x16 grid).
  const int d = blockIdx.y * 16 + blockIdx.x;
  const int q = d >> 3;
  const int xcd = d & 7;
  const int bnid = xcd * 2 + (q >> 4);  // 0..15
  const int bmid = q & 15;              // 0..15
  const int bm = bmid * 256;
  const int bn = bnid * 256;

  v16i acc[2][4];
#pragma unroll
  for (int i = 0; i < 2; ++i)
#pragma unroll
    for (int j = 0; j < 4; ++j)
#pragma unroll
      for (int q2 = 0; q2 < 16; ++q2) acc[i][j][q2] = 0;

  // A staging: thread t -> LDS row srow (+128), 16B slot (t&3); slot holds
  // global chunk (t&3)^((row>>1)&3); key (t>>3)&3 invariant under +128.
  const int srow = t >> 2;  // 0..127
  const int cswz = ((t & 3) ^ ((t >> 3) & 3)) * 16;
  const char* gA = A + (size_t)(bm + srow) * Kdim + cswz;

#define STG_A(buf_off, koff)                                                  \
  do {                                                                        \
    _Pragma("unroll") for (int i = 0; i < 2; ++i)                             \
        gload_lds16(gA + (koff) + (size_t)i * 128 * Kdim,                     \
                    lds + (buf_off) + i * 8192 + t * 16);                     \
  } while (0)

  const int arow = warow * 64 + (l & 31);
  const int lhalf = l >> 5;
  const int lkey = (l >> 1) & 3;  // == (frag_row>>1)&3 for all frag rows
  const int slot0 = ((0 + lhalf) ^ lkey) * 16;  // ks=0 16B slot
  const int slot1 = ((2 + lhalf) ^ lkey) * 16;  // ks=1 16B slot

  // B fragment base for this wave: nblk = bnid*8 + wbcol*4 + j.
  const char* gBf =
      B + (size_t)(bnid * 8 + wbcol * 4) * 131072 + (size_t)l * 16;

  // Frag register banks: [bank][ks][frag].
  v4i fa[2][2][2];  // 32 VGPR
  v4i fb[2][2][4];  // 64 VGPR

#define READF_A(BK, RBO)                                                      \
  do {                                                                        \
    const char* As_ = lds + (RBO);                                            \
    _Pragma("unroll") for (int i = 0; i < 2; ++i) {                           \
      fa[BK][0][i] = *(const v4i*)(As_ + (arow + i * 32) * 64 + slot0);       \
      fa[BK][1][i] = *(const v4i*)(As_ + (arow + i * 32) * 64 + slot1);       \
    }                                                                         \
  } while (0)

#define READ_B(BK, kt_)                                                       \
  do {                                                                        \
    _Pragma("unroll") for (int j = 0; j < 4; ++j)                             \
        _Pragma("unroll") for (int ks = 0; ks < 2; ++ks)                      \
            fb[BK][ks][j] = *(const v4i*)(gBf + (size_t)j * 131072 +          \
                                          (size_t)(kt_)*2048 + ks * 1024);    \
  } while (0)

#define MFMA(a, b, c) __builtin_amdgcn_mfma_i32_32x32x32_i8(a, b, c, 0, 0, 0)
#define SETP(n) __builtin_amdgcn_s_setprio(n)
#define BAR()                                                                 \
  do {                                                                        \
    asm volatile("" ::: "memory");                                            \
    __builtin_amdgcn_s_barrier();                                             \
    asm volatile("" ::: "memory");                                            \
  } while (0)
#define WAITV(n) asm volatile("s_waitcnt vmcnt(" #n ")" ::: "memory")

#define DOMFMA(BK)                                                            \
  do {                                                                        \
    SETP(1);                                                                  \
    _Pragma("unroll") for (int ks = 0; ks < 2; ++ks)                          \
        _Pragma("unroll") for (int i = 0; i < 2; ++i)                         \
            _Pragma("unroll") for (int j = 0; j < 4; ++j)                     \
                acc[i][j] = MFMA(fa[BK][ks][i], fb[BK][ks][j], acc[i][j]);    \
    SETP(0);                                                                  \
  } while (0)

// Steady-state tile kt: load bank LBK=(kt+1)&1 (frags kt+1), stage A(kt+3),
// compute bank CBK=kt&1. WAITV(10) leaves exactly this tile's 10 vmem ops
// outstanding -> certifies B(kt) (consumed now) and A(kt+2) staging (read
// next tile, globally certified by the BAR).
#define TILE(LBK, RBO, SBO, SKOFF, KB, CBK)                                   \
  do {                                                                        \
    READF_A(LBK, RBO);                                                        \
    READ_B(LBK, KB);                                                          \
    STG_A(SBO, SKOFF);                                                        \
    WAITV(10);                                                                \
    DOMFMA(CBK);                                                              \
    BAR();                                                                    \
  } while (0)

  // Prologue: stage A tiles 0..2; fence so the 8 B0 loads are provably the
  // newest vmem; WAITV(8) certifies all A staging; read bank0 frags(0).
  STG_A(0, 0);
  STG_A(16384, 64);
  STG_A(32768, 128);
  __builtin_amdgcn_sched_barrier(0);
  READ_B(0, 0);
  WAITV(8);
  BAR();
  READF_A(0, 0);

  // Tiles 0..59 (x4-unrolled: constant buffer offsets), then peel 60..63.
#pragma unroll 1
  for (int kt = 0; kt < 60; kt += 4) {
    TILE(1, 16384, 49152, (kt + 3) * 64, kt + 1, 0);
    TILE(0, 32768, 0, (kt + 4) * 64, kt + 2, 1);
    TILE(1, 49152, 16384, (kt + 5) * 64, kt + 3, 0);
    TILE(0, 0, 32768, (kt + 6) * 64, kt + 4, 1);
  }
  TILE(1, 16384, 49152, 63 * 64, 61, 0);  // kt=60: stages A63, loads frags61
  // kt=61: no more staging. WAITV(8) drains B61 (consumed) + A63 (certified
  // at the BAR for kt=62's READF of buf3).
  READF_A(0, 32768);
  READ_B(0, 62);
  WAITV(8);
  DOMFMA(1);
  BAR();
  // kt=62: WAITV(8) drains B62.
  READF_A(1, 49152);
  READ_B(1, 63);
  WAITV(8);
  DOMFMA(0);
  // kt=63: drain B63.
  WAITV(0);
  DOMFMA(1);

  // Epilogue. C/D 32x32 layout: col=lane&31, row=(r&3)+8*(r>>2)+4*(lane>>5)
  const int col = l & 31;
#pragma unroll
  for (int i = 0; i < 2; ++i) {
    const int gm0 = bm + warow * 64 + i * 32;
#pragma unroll
    for (int j = 0; j < 4; ++j) {
      const int gn = bn + wbcol * 128 + j * 32 + col;
      const int cs = 66 * csy[gn] - 8650752;  // -2112*4096
#pragma unroll
      for (int r = 0; r < 16; ++r) {
        const int row = (r & 3) + 8 * (r >> 2) + 4 * lhalf;
        const int gm = gm0 + row;
        const int val = acc[i][j][r] - 32 * rsx[gm] + cs;
        out[(size_t)gm * Ndim + gn] = 7.5e-4f * (float)val;
      }
    }
  }
#undef STG_A
#undef READF_A
#undef READ_B
#undef TILE
#undef DOMFMA
#undef MFMA
#undef SETP
#undef BAR
#undef WAITV
}

extern "C" void kernel_launch(void* const* d_in, const int* in_sizes, int n_in,
                              void* d_out, int out_size, void* d_ws, size_t ws_size,
                              hipStream_t stream) {
  (void)in_sizes; (void)n_in; (void)out_size; (void)ws_size;
  const int* x = (const int*)d_in[0];
  const int* y = (const int*)d_in[1];
  float* out = (float*)d_out;
  char* ws = (char*)d_ws;
  char* x8 = ws;                                          // 16 MB
  char* yt = ws + (size_t)Mdim * Kdim;                    // 16 MB (frag order)
  int* rsx = (int*)(ws + (size_t)Mdim * Kdim + (size_t)Kdim * Ndim);
  int* csy = rsx + Mdim;

  hipMemsetAsync(csy, 0, Ndim * sizeof(int), stream);
  pack_x_kernel<<<Mdim, 256, 0, stream>>>(x, x8, rsx);
  pack_yt_kernel<<<dim3(Ndim / 64, Kdim / 64), 256, 0, stream>>>(y, yt, csy);
  gemm_i8_kernel<<<dim3(Ndim / 256, Mdim / 256), 512, 0, stream>>>(x8, yt, rsx, csy, out);
}

// Round 5
// 236.249 us; speedup vs baseline: 1.0522x; 1.0522x over previous
//
#include <hip/hip_runtime.h>
#include <stdint.h>

#define Mdim 4096
#define Kdim 4096
#define Ndim 4096

typedef __attribute__((ext_vector_type(4))) int v4i;
typedef __attribute__((ext_vector_type(16))) int v16i;

__device__ __forceinline__ void gload_lds16(const void* g, void* l) {
  __builtin_amdgcn_global_load_lds(
      (__attribute__((address_space(1))) void*)(uintptr_t)g,
      (__attribute__((address_space(3))) void*)(uint32_t)(uintptr_t)l,
      16, 0, 0);
}

// ---- fused pack: blocks [0,4096) pack x rows; [4096,8192) pack y tiles ----
// x path: int32 [M][K] -> int8 [M][K] + row sums. Loads 4x int4 (64B/lane),
// stores ONE int4 (16B/lane, was 4x dword) -- G13 vectorized writes.
// y path: int32 [K][N] -> int8 (y-128) [N][K] row-major + colsum via LDS
// 64x64 transpose (identical to the measured R2 pack_yt).
__global__ __launch_bounds__(256) void pack_fused_kernel(
    const int* __restrict__ x, const int* __restrict__ y,
    char* __restrict__ x8, char* __restrict__ yt, int* __restrict__ rsx,
    int* __restrict__ csy) {
  __shared__ int wt[64 * 17];
  const int t = threadIdx.x;
  if (blockIdx.x < Mdim) {
    // ---------------- pack x row ----------------
    const int row = blockIdx.x;
    const int4* src = (const int4*)(x + (size_t)row * Kdim);
    int4* dst = (int4*)(x8 + (size_t)row * Kdim);
    int sum = 0;
    int wd[4];
#pragma unroll
    for (int i = 0; i < 4; ++i) {
      int4 v = src[t * 4 + i];
      sum += v.x + v.y + v.z + v.w;
      wd[i] = (v.x & 0xff) | ((v.y & 0xff) << 8) | ((v.z & 0xff) << 16) |
              (v.w << 24);
    }
    dst[t] = make_int4(wd[0], wd[1], wd[2], wd[3]);
#pragma unroll
    for (int o = 32; o > 0; o >>= 1) sum += __shfl_down(sum, o, 64);
    if ((t & 63) == 0) wt[t >> 6] = sum;
    __syncthreads();
    if (t == 0) rsx[row] = wt[0] + wt[1] + wt[2] + wt[3];
  } else {
    // ---------------- pack+transpose y 64x64 tile ----------------
    const int bidx = blockIdx.x - Mdim;
    const int n0 = (bidx & 63) * 64;
    const int k0 = (bidx >> 6) * 64;
    const int c = t & 15;   // n-quad
    const int r0 = t >> 4;  // 0..15
#pragma unroll
    for (int s = 0; s < 4; ++s) {
      const int r = r0 + s * 16;  // k row 0..63
      int4 v = *(const int4*)(y + (size_t)(k0 + r) * Ndim + n0 + c * 4);
      v.x -= 128; v.y -= 128; v.z -= 128; v.w -= 128;
      wt[r * 17 + c] = (v.x & 0xff) | ((v.y & 0xff) << 8) |
                       ((v.z & 0xff) << 16) | (v.w << 24);
    }
    __syncthreads();
    const int n = t >> 2;         // 0..63
    const int kq = t & 3;         // 16-k chunk
    const int colw = n >> 2;      // LDS word column
    const int byi = (n & 3) * 8;  // byte select
    int outw[4];
    int bsum = 0;
#pragma unroll
    for (int j = 0; j < 4; ++j) {
      int b[4];
#pragma unroll
      for (int jj = 0; jj < 4; ++jj) {
        const int word = wt[(kq * 16 + j * 4 + jj) * 17 + colw];
        b[jj] = (word >> byi) & 0xff;
        bsum += (int)(char)b[jj];
      }
      outw[j] = b[0] | (b[1] << 8) | (b[2] << 16) | (b[3] << 24);
    }
    *(int4*)(yt + (size_t)(n0 + n) * Kdim + k0 + kq * 16) =
        make_int4(outw[0], outw[1], outw[2], outw[3]);
    bsum += __shfl_xor(bsum, 1, 64);
    bsum += __shfl_xor(bsum, 2, 64);
    if (kq == 0) atomicAdd(csy + n0 + n, bsum);
  }
}

// ---- i8 GEMM: C = 7.5e-4*(A8 @ B8^T - 32*rsx[m] + 66*csy[n] - 2112*K) ------
// VERBATIM the best-measured variant (R2, 76.0us): 512 thr / 8 waves, tile
// 256x256, BK=64, 4-phase split per K-tile, 3 LDS buffers, counted vmcnt(4),
// setprio around MFMA clusters. Do not touch this round (attribution).
__global__ __launch_bounds__(512, 2) void gemm_i8_kernel(
    const char* __restrict__ A, const char* __restrict__ B,
    const int* __restrict__ rsx, const int* __restrict__ csy,
    float* __restrict__ out) {
  __shared__ __align__(16) char lds[3 * 32768];  // buf: [As 16K | Bs 16K] x3
  const int t = threadIdx.x;
  const int l = t & 63;
  const int w = t >> 6;      // 0..7
  const int warow = w >> 1;  // 0..3 (x64 rows)
  const int wbcol = w & 1;   // 0..1 (x128 cols)
  const int bm = blockIdx.y * 256;
  const int bn = blockIdx.x * 256;

  v16i acc[2][4];
#pragma unroll
  for (int i = 0; i < 2; ++i)
#pragma unroll
    for (int j = 0; j < 4; ++j)
#pragma unroll
      for (int q = 0; q < 16; ++q) acc[i][j][q] = 0;

  const int srow = t >> 2;  // 0..127
  const int cswz = ((t & 3) ^ ((t >> 3) & 3)) * 16;
  const char* gA = A + (size_t)(bm + srow) * Kdim + cswz;
  const char* gB = B + (size_t)(bn + srow) * Kdim + cswz;

#define STAGE(buf_off, koff)                                                  \
  do {                                                                        \
    _Pragma("unroll") for (int i = 0; i < 2; ++i)                             \
        gload_lds16(gA + (koff) + (size_t)i * 128 * Kdim,                     \
                    lds + (buf_off) + i * 8192 + t * 16);                     \
    _Pragma("unroll") for (int i = 0; i < 2; ++i)                             \
        gload_lds16(gB + (koff) + (size_t)i * 128 * Kdim,                     \
                    lds + (buf_off) + 16384 + i * 8192 + t * 16);             \
  } while (0)

#define STG(sbo, koff, idx)                                                   \
  gload_lds16(((idx) < 2 ? gA : gB) + (koff) + (size_t)((idx)&1) * 128 * Kdim,\
              lds + (sbo) + ((idx) < 2 ? 0 : 16384) + ((idx)&1) * 8192 +      \
                  t * 16)

  const int arow = warow * 64 + (l & 31);
  const int brow = wbcol * 128 + (l & 31);
  const int lhalf = l >> 5;
  const int lkey = (l >> 1) & 3;
  const int slot0 = ((0 + lhalf) ^ lkey) * 16;
  const int slot1 = ((2 + lhalf) ^ lkey) * 16;

#define MFMA(a, b, c) __builtin_amdgcn_mfma_i32_32x32x32_i8(a, b, c, 0, 0, 0)
#define SETP(n) __builtin_amdgcn_s_setprio(n)
#define FENCE() __builtin_amdgcn_sched_barrier(0)
#define BAR()                                                                 \
  do {                                                                        \
    asm volatile("" ::: "memory");                                            \
    __builtin_amdgcn_s_barrier();                                             \
    asm volatile("" ::: "memory");                                            \
  } while (0)
#define WAITV(n) asm volatile("s_waitcnt vmcnt(" #n ")" ::: "memory")

#define TILE(bo, sbo, skoff, dostage, TAILWAIT)                               \
  do {                                                                        \
    const char* As = lds + (bo);                                              \
    const char* Bs = lds + (bo) + 16384;                                      \
    v4i a0, a1, b0, b1;                                                       \
    a0 = *(const v4i*)(As + arow * 64 + slot0);                               \
    a1 = *(const v4i*)(As + (arow + 32) * 64 + slot0);                        \
    b0 = *(const v4i*)(Bs + brow * 64 + slot0);                               \
    b1 = *(const v4i*)(Bs + (brow + 32) * 64 + slot0);                        \
    if (dostage) STG(sbo, skoff, 0);                                          \
    BAR();                                                                    \
    FENCE();                                                                  \
    SETP(1);                                                                  \
    acc[0][0] = MFMA(a0, b0, acc[0][0]);                                      \
    acc[0][1] = MFMA(a0, b1, acc[0][1]);                                      \
    acc[1][0] = MFMA(a1, b0, acc[1][0]);                                      \
    acc[1][1] = MFMA(a1, b1, acc[1][1]);                                      \
    SETP(0);                                                                  \
    FENCE();                                                                  \
    BAR();                                                                    \
    {                                                                         \
      v4i b2 = *(const v4i*)(Bs + (brow + 64) * 64 + slot0);                  \
      v4i b3 = *(const v4i*)(Bs + (brow + 96) * 64 + slot0);                  \
      if (dostage) STG(sbo, skoff, 1);                                        \
      BAR();                                                                  \
      FENCE();                                                                \
      SETP(1);                                                                \
      acc[0][2] = MFMA(a0, b2, acc[0][2]);                                    \
      acc[0][3] = MFMA(a0, b3, acc[0][3]);                                    \
      acc[1][2] = MFMA(a1, b2, acc[1][2]);                                    \
      acc[1][3] = MFMA(a1, b3, acc[1][3]);                                    \
      SETP(0);                                                                \
      FENCE();                                                                \
      BAR();                                                                  \
    }                                                                         \
    a0 = *(const v4i*)(As + arow * 64 + slot1);                               \
    a1 = *(const v4i*)(As + (arow + 32) * 64 + slot1);                        \
    b0 = *(const v4i*)(Bs + brow * 64 + slot1);                               \
    b1 = *(const v4i*)(Bs + (brow + 32) * 64 + slot1);                        \
    if (dostage) STG(sbo, skoff, 2);                                          \
    BAR();                                                                    \
    FENCE();                                                                  \
    SETP(1);                                                                  \
    acc[0][0] = MFMA(a0, b0, acc[0][0]);                                      \
    acc[0][1] = MFMA(a0, b1, acc[0][1]);                                      \
    acc[1][0] = MFMA(a1, b0, acc[1][0]);                                      \
    acc[1][1] = MFMA(a1, b1, acc[1][1]);                                      \
    SETP(0);                                                                  \
    FENCE();                                                                  \
    BAR();                                                                    \
    {                                                                         \
      v4i b2 = *(const v4i*)(Bs + (brow + 64) * 64 + slot1);                  \
      v4i b3 = *(const v4i*)(Bs + (brow + 96) * 64 + slot1);                  \
      if (dostage) STG(sbo, skoff, 3);                                        \
      BAR();                                                                  \
      FENCE();                                                                \
      SETP(1);                                                                \
      acc[0][2] = MFMA(a0, b2, acc[0][2]);                                    \
      acc[0][3] = MFMA(a0, b3, acc[0][3]);                                    \
      acc[1][2] = MFMA(a1, b2, acc[1][2]);                                    \
      acc[1][3] = MFMA(a1, b3, acc[1][3]);                                    \
      SETP(0);                                                                \
      FENCE();                                                                \
      TAILWAIT;                                                               \
      BAR();                                                                  \
    }                                                                         \
  } while (0)

  STAGE(0, 0);
  STAGE(32768, 64);
  WAITV(4);
  BAR();

#pragma unroll 1
  for (int kt = 0; kt < 60; kt += 3) {
    TILE(0, 65536, (kt + 2) * 64, 1, WAITV(4));
    TILE(32768, 0, (kt + 3) * 64, 1, WAITV(4));
    TILE(65536, 32768, (kt + 4) * 64, 1, WAITV(4));
  }
  TILE(0, 65536, 62 * 64, 1, WAITV(4));  // kt=60, stages t62
  TILE(32768, 0, 63 * 64, 1, WAITV(4));  // kt=61, stages t63
  TILE(65536, 0, 0, 0, WAITV(0));        // kt=62, drain t63
  TILE(0, 0, 0, 0, (void)0);             // kt=63

  const int col = l & 31;
#pragma unroll
  for (int i = 0; i < 2; ++i) {
    const int gm0 = bm + warow * 64 + i * 32;
#pragma unroll
    for (int j = 0; j < 4; ++j) {
      const int gn = bn + wbcol * 128 + j * 32 + col;
      const int cs = 66 * csy[gn] - 8650752;  // -2112*4096
#pragma unroll
      for (int r = 0; r < 16; ++r) {
        const int row = (r & 3) + 8 * (r >> 2) + 4 * lhalf;
        const int gm = gm0 + row;
        const int val = acc[i][j][r] - 32 * rsx[gm] + cs;
        out[(size_t)gm * Ndim + gn] = 7.5e-4f * (float)val;
      }
    }
  }
#undef STAGE
#undef STG
#undef TILE
#undef MFMA
#undef SETP
#undef FENCE
#undef BAR
#undef WAITV
}

extern "C" void kernel_launch(void* const* d_in, const int* in_sizes, int n_in,
                              void* d_out, int out_size, void* d_ws, size_t ws_size,
                              hipStream_t stream) {
  (void)in_sizes; (void)n_in; (void)out_size; (void)ws_size;
  const int* x = (const int*)d_in[0];
  const int* y = (const int*)d_in[1];
  float* out = (float*)d_out;
  char* ws = (char*)d_ws;
  char* x8 = ws;                                          // 16 MB
  char* yt = ws + (size_t)Mdim * Kdim;                    // 16 MB (row-major)
  int* rsx = (int*)(ws + (size_t)Mdim * Kdim + (size_t)Kdim * Ndim);
  int* csy = rsx + Mdim;

  hipMemsetAsync(csy, 0, Ndim * sizeof(int), stream);
  pack_fused_kernel<<<Mdim + (Ndim / 64) * (Kdim / 64), 256, 0, stream>>>(
      x, y, x8, yt, rsx, csy);
  gemm_i8_kernel<<<dim3(Ndim / 256, Mdim / 256), 512, 0, stream>>>(x8, yt, rsx,
                                                                   csy, out);
}